// Round 1
// baseline (2998.796 us; speedup 1.0000x reference)
//
#include <hip/hip_runtime.h>
#include <hip/hip_bf16.h>
#include <math.h>

#define NPOS 4900
#define NG1  708
#define NG2  4192
#define INF  512
#define OUTF 256
#define JPAD 4928   // 77*64, padded j-dim for B buffers
#define G1T  45     // ceil(708/16)
#define G2T  262    // 4192/16
#define QT   307    // G1T + G2T

// ---------------------------------------------------------------------------
// K0: rp = r @ Wr + br  (4x256); store S[0]=rp[ridx], S[1]=rp[2], S[2]=rp[3]
// ---------------------------------------------------------------------------
__global__ __launch_bounds__(256) void k0_rp(
    const float* __restrict__ r, const float* __restrict__ Wr,
    const float* __restrict__ br, const int* __restrict__ flagp,
    float* __restrict__ S)
{
    __shared__ float rsh[1024];
    int t = threadIdx.x;
    for (int i = t; i < 1024; i += 256) rsh[i] = r[i];
    __syncthreads();
    float a0 = 0.f, a1 = 0.f, a2 = 0.f, a3 = 0.f;
    for (int c = 0; c < 256; ++c) {
        float w = Wr[c * 256 + t];
        a0 += rsh[c] * w;
        a1 += rsh[256 + c] * w;
        a2 += rsh[512 + c] * w;
        a3 += rsh[768 + c] * w;
    }
    float b = br[t];
    a0 += b; a1 += b; a2 += b; a3 += b;
    int ridx = (flagp[0] != 0) ? 1 : 0;
    S[t]         = ridx ? a1 : a0;
    S[256 + t]   = a2;
    S[512 + t]   = a3;
}

// ---------------------------------------------------------------------------
// K1: fused projections hQ/hK/hV/H = feature @ {Wq,Wk,Wv,Ww} + bias
// GEMM M=4900 K=512, per-matrix N=256. Tile 64x128, BK=16.
// ---------------------------------------------------------------------------
__global__ __launch_bounds__(256) void k1_proj(
    const float* __restrict__ feat,
    const float* __restrict__ Wq, const float* __restrict__ bq,
    const float* __restrict__ Wk, const float* __restrict__ bk,
    const float* __restrict__ Wv, const float* __restrict__ bv,
    const float* __restrict__ Ww, const float* __restrict__ bw,
    float* __restrict__ hQ, float* __restrict__ hK,
    float* __restrict__ hV, float* __restrict__ Hb)
{
    __shared__ float AT[16][68];    // [k][m]
    __shared__ float Bs[16][132];   // [k][n]
    int t = threadIdx.x;
    int mat = blockIdx.x >> 1;
    int n0  = (blockIdx.x & 1) * 128;
    int m0  = blockIdx.y * 64;
    const float* W; const float* bias; float* dst;
    switch (mat) {
        case 0:  W = Wq; bias = bq; dst = hQ; break;
        case 1:  W = Wk; bias = bk; dst = hK; break;
        case 2:  W = Wv; bias = bv; dst = hV; break;
        default: W = Ww; bias = bw; dst = Hb; break;
    }
    float acc[4][8];
#pragma unroll
    for (int i = 0; i < 4; ++i)
#pragma unroll
        for (int j = 0; j < 8; ++j) acc[i][j] = 0.f;
    int mg = (t >> 4) * 4, jg = (t & 15) * 8;
    int am = t & 63, ak = (t >> 6) * 4;
    int bkk = t >> 4, bn = (t & 15) * 8;
    for (int k0 = 0; k0 < INF; k0 += 16) {
        __syncthreads();
        {
            int row = m0 + am;
            float4 v = make_float4(0.f, 0.f, 0.f, 0.f);
            if (row < NPOS) v = *(const float4*)(feat + (size_t)row * INF + k0 + ak);
            AT[ak + 0][am] = v.x; AT[ak + 1][am] = v.y;
            AT[ak + 2][am] = v.z; AT[ak + 3][am] = v.w;
        }
        {
            const float* p = W + (size_t)(k0 + bkk) * OUTF + n0 + bn;
            float4 u0 = *(const float4*)p;
            float4 u1 = *(const float4*)(p + 4);
            *(float4*)&Bs[bkk][bn]     = u0;
            *(float4*)&Bs[bkk][bn + 4] = u1;
        }
        __syncthreads();
#pragma unroll
        for (int kk = 0; kk < 16; ++kk) {
            float4 a  = *(const float4*)&AT[kk][mg];
            float4 b0 = *(const float4*)&Bs[kk][jg];
            float4 b1 = *(const float4*)&Bs[kk][jg + 4];
            float av[4] = {a.x, a.y, a.z, a.w};
            float bv_[8] = {b0.x, b0.y, b0.z, b0.w, b1.x, b1.y, b1.z, b1.w};
#pragma unroll
            for (int i = 0; i < 4; ++i)
#pragma unroll
                for (int j = 0; j < 8; ++j) acc[i][j] += av[i] * bv_[j];
        }
    }
#pragma unroll
    for (int i = 0; i < 4; ++i) {
        int row = m0 + mg + i;
        if (row < NPOS) {
#pragma unroll
            for (int j = 0; j < 8; ++j) {
                int n = n0 + jg + j;
                dst[(size_t)row * OUTF + n] = acc[i][j] + bias[n];
            }
        }
    }
}

// ---------------------------------------------------------------------------
// K2: Ball[(v,h,dd)][j] = sum_k ( hKview[h*L+k][dd] * 0.5*S[v+part][(k&3)*64+dd] ) * adj[krow][j]
// part=0 (k in group1, K=708) -> B1 ; part=1 (group2, K=4192 split in 2) -> B2a/B2b
// Tile: M=64 (one (v,h)), N=128, BK=16.
// ---------------------------------------------------------------------------
__global__ __launch_bounds__(256) void k2_pgemm(
    const float* __restrict__ hK, const float* __restrict__ adj,
    const float* __restrict__ S,
    float* __restrict__ B1, float* __restrict__ B2a, float* __restrict__ B2b)
{
    __shared__ float AT[16][68];    // [kk][dd]
    __shared__ float Bs[16][132];   // [kk][j]
    int t = threadIdx.x;
    int j0 = blockIdx.x * 128;
    int v = blockIdx.y >> 2, h = blockIdx.y & 3;
    int z = blockIdx.z;
    int part = (z > 0) ? 1 : 0;
    int L = part ? NG2 : NG1;
    int kvbase = part ? (z - 1) * 2096 : 0;
    int Ksteps = part ? 131 : 45;
    const float* kviewbase = hK + (part ? NG1 * OUTF : 0) + (size_t)h * L * 64;
    const float* sv = S + (v + part) * 256;
    int rowoff = part ? NG1 : 0;
    float* dst = (z == 0) ? B1 : ((z == 1) ? B2a : B2b);
    dst += (size_t)((v * 4 + h) * 64) * JPAD;

    float acc[4][8];
#pragma unroll
    for (int i = 0; i < 4; ++i)
#pragma unroll
        for (int j = 0; j < 8; ++j) acc[i][j] = 0.f;
    int ddg = (t >> 4) * 4, jg = (t & 15) * 8;
    int akk = t >> 4, add4 = (t & 15) * 4;
    int bkk = t >> 4, bj = (t & 15) * 8;

    for (int ks = 0; ks < Ksteps; ++ks) {
        int k0 = kvbase + ks * 16;
        __syncthreads();
        {
            int kv = k0 + akk;
            float4 a = make_float4(0.f, 0.f, 0.f, 0.f);
            if (kv < L) {
                float4 x  = *(const float4*)(kviewbase + (size_t)kv * 64 + add4);
                float4 s4 = *(const float4*)(sv + (kv & 3) * 64 + add4);
                a = make_float4(0.5f * x.x * s4.x, 0.5f * x.y * s4.y,
                                0.5f * x.z * s4.z, 0.5f * x.w * s4.w);
            }
            *(float4*)&AT[akk][add4] = a;
        }
        {
            int kv = k0 + bkk;
            int arow = rowoff + kv;
            if (kv < L && (j0 + bj + 7) < NPOS) {
                const float* p = adj + (size_t)arow * NPOS + j0 + bj;
                float4 u0 = *(const float4*)p;
                float4 u1 = *(const float4*)(p + 4);
                *(float4*)&Bs[bkk][bj]     = u0;
                *(float4*)&Bs[bkk][bj + 4] = u1;
            } else {
#pragma unroll
                for (int j = 0; j < 8; ++j) {
                    int jj = j0 + bj + j;
                    Bs[bkk][bj + j] = (kv < L && jj < NPOS)
                        ? adj[(size_t)arow * NPOS + jj] : 0.f;
                }
            }
        }
        __syncthreads();
#pragma unroll
        for (int kk = 0; kk < 16; ++kk) {
            float4 a  = *(const float4*)&AT[kk][ddg];
            float4 b0 = *(const float4*)&Bs[kk][jg];
            float4 b1 = *(const float4*)&Bs[kk][jg + 4];
            float av[4] = {a.x, a.y, a.z, a.w};
            float bv_[8] = {b0.x, b0.y, b0.z, b0.w, b1.x, b1.y, b1.z, b1.w};
#pragma unroll
            for (int i = 0; i < 4; ++i)
#pragma unroll
                for (int j = 0; j < 8; ++j) acc[i][j] += av[i] * bv_[j];
        }
    }
#pragma unroll
    for (int i = 0; i < 4; ++i) {
        float* drow = dst + (size_t)(ddg + i) * JPAD;
#pragma unroll
        for (int j = 0; j < 8; ++j) {
            int jj = j0 + jg + j;
            if (jj < NPOS) drow[jj] = acc[i][j];
        }
    }
}

// ---------------------------------------------------------------------------
// K3: fused  alpha2 = Qscaled @ Ball (K=128)  -> head-softmax -> m += alpha @ V
// Block: 16 q-positions (one group) x all 4 heads; j-loop over one half (77x32).
// m written as partial (2 j-halves) to mpart[2][4900][256].
// ---------------------------------------------------------------------------
__global__ __launch_bounds__(256, 2) void k3_fused(
    const float* __restrict__ hQ, const float* __restrict__ hV,
    const float* __restrict__ S,
    const float* __restrict__ B1, const float* __restrict__ B2a,
    const float* __restrict__ B2b,
    float* __restrict__ mpart)
{
    __shared__ float AT[128][68];     // [k=p*64+d][h*16+qq]  Q-side (scaled), fp32
    __shared__ float VL[4][32][68];   // [h][j][dd] V tile
    __shared__ float aF[4][16][36];   // raw logits -> alpha (in place)
    int t = threadIdx.x;
    int jhalf = blockIdx.x & 1;
    int qt = blockIdx.x >> 1;
    int g, q0, L, vbase, posbase;
    if (qt < G1T) { g = 0; q0 = qt * 16;          L = NG1; vbase = 0;          posbase = 0; }
    else          { g = 1; q0 = (qt - G1T) * 16;  L = NG2; vbase = NG1 * OUTF; posbase = NG1; }

    // stage AT (once)
    {
        int qq = t & 15, hh = (t >> 4) & 3, hf = t >> 6;
        int q = q0 + qq;
        bool qvalid = (q < L);
        const float* qrow = hQ + vbase + (size_t)(hh * L + q) * 64;
        int c = q & 3;
#pragma unroll
        for (int p = 0; p < 2; ++p) {
            const float* sp = S + (g + p) * 256 + c * 64;
#pragma unroll
            for (int d0 = 0; d0 < 16; d0 += 4) {
                int d = hf * 16 + d0;
                float4 x = make_float4(0.f, 0.f, 0.f, 0.f);
                if (qvalid) {
                    float4 qv4 = *(const float4*)(qrow + d);
                    float4 s4  = *(const float4*)(sp + d);
                    x = make_float4(qv4.x * s4.x, qv4.y * s4.y, qv4.z * s4.z, qv4.w * s4.w);
                }
                AT[p * 64 + d + 0][hh * 16 + qq] = x.x;
                AT[p * 64 + d + 1][hh * 16 + qq] = x.y;
                AT[p * 64 + d + 2][hh * 16 + qq] = x.z;
                AT[p * 64 + d + 3][hh * 16 + qq] = x.w;
            }
        }
    }

    int h1 = t >> 6;                        // head for phase1/phase2
    int qq4 = ((t >> 4) & 3) * 4, jl2 = (t & 15) * 2;
    int qq2 = (t >> 2) & 15, ddg = (t & 3) * 16;
    int vu = t & 63, vjj = vu >> 1, vdd = (vu & 1) * 32;

    float macc[16];
#pragma unroll
    for (int i = 0; i < 16; ++i) macc[i] = 0.f;

    const int rowb = (g * 4 + h1) * 64;
    const float* b1base  = B1  + (size_t)rowb * JPAD + jl2;
    const float* b2abase = B2a + (size_t)rowb * JPAD + jl2;
    const float* b2bbase = B2b + (size_t)rowb * JPAD + jl2;

    for (int jt = 0; jt < 77; ++jt) {
        int j0 = (jhalf * 77 + jt) * 32;
        __syncthreads();    // prev phase2 done with VL/aF
        // stage V tile
        {
            int j = j0 + vjj;
            const float* vrow = hV + (size_t)(h1 * NPOS + j) * 64 + vdd;
#pragma unroll
            for (int d0 = 0; d0 < 32; d0 += 4) {
                float4 x = make_float4(0.f, 0.f, 0.f, 0.f);
                if (j < NPOS) x = *(const float4*)(vrow + d0);
                *(float4*)&VL[h1][vjj][vdd + d0] = x;
            }
        }
        // phase1: alpha2 tile, K=128 (two 64-halves: B1 then B2a+B2b)
        float a2[4][2];
#pragma unroll
        for (int i = 0; i < 4; ++i) { a2[i][0] = 0.f; a2[i][1] = 0.f; }
        {
            const float* bp = b1base + j0;
#pragma unroll 8
            for (int k = 0; k < 64; ++k) {
                float4 a = *(const float4*)&AT[k][h1 * 16 + qq4];
                float2 b = *(const float2*)(bp + (size_t)k * JPAD);
                a2[0][0] += a.x * b.x; a2[0][1] += a.x * b.y;
                a2[1][0] += a.y * b.x; a2[1][1] += a.y * b.y;
                a2[2][0] += a.z * b.x; a2[2][1] += a.z * b.y;
                a2[3][0] += a.w * b.x; a2[3][1] += a.w * b.y;
            }
            const float* bpa = b2abase + j0;
            const float* bpb = b2bbase + j0;
#pragma unroll 8
            for (int k = 0; k < 64; ++k) {
                float4 a = *(const float4*)&AT[64 + k][h1 * 16 + qq4];
                float2 ba = *(const float2*)(bpa + (size_t)k * JPAD);
                float2 bb = *(const float2*)(bpb + (size_t)k * JPAD);
                float bx = ba.x + bb.x, by = ba.y + bb.y;
                a2[0][0] += a.x * bx; a2[0][1] += a.x * by;
                a2[1][0] += a.y * bx; a2[1][1] += a.y * by;
                a2[2][0] += a.z * bx; a2[2][1] += a.z * by;
                a2[3][0] += a.w * bx; a2[3][1] += a.w * by;
            }
        }
#pragma unroll
        for (int i = 0; i < 4; ++i) {
            aF[h1][qq4 + i][jl2 + 0] = a2[i][0];
            aF[h1][qq4 + i][jl2 + 1] = a2[i][1];
        }
        __syncthreads();
        // softmax over heads, in place (each (qq,j) pair handled by one thread)
#pragma unroll
        for (int pi = 0; pi < 2; ++pi) {
            int p = t * 2 + pi;
            int qq = p >> 5, j = p & 31;
            float v0 = aF[0][qq][j], v1 = aF[1][qq][j];
            float v2 = aF[2][qq][j], v3 = aF[3][qq][j];
            float mx = fmaxf(fmaxf(v0, v1), fmaxf(v2, v3));
            float e0 = __expf(v0 - mx), e1 = __expf(v1 - mx);
            float e2 = __expf(v2 - mx), e3 = __expf(v3 - mx);
            float inv = 1.0f / (e0 + e1 + e2 + e3);
            aF[0][qq][j] = e0 * inv; aF[1][qq][j] = e1 * inv;
            aF[2][qq][j] = e2 * inv; aF[3][qq][j] = e3 * inv;
        }
        __syncthreads();
        // phase2: m += alpha @ V
#pragma unroll 4
        for (int j = 0; j < 32; ++j) {
            float al = aF[h1][qq2][j];
            const float* vr = &VL[h1][j][ddg];
            float4 w0 = *(const float4*)vr;
            float4 w1 = *(const float4*)(vr + 4);
            float4 w2 = *(const float4*)(vr + 8);
            float4 w3 = *(const float4*)(vr + 12);
            macc[0]  += al * w0.x; macc[1]  += al * w0.y; macc[2]  += al * w0.z; macc[3]  += al * w0.w;
            macc[4]  += al * w1.x; macc[5]  += al * w1.y; macc[6]  += al * w1.z; macc[7]  += al * w1.w;
            macc[8]  += al * w2.x; macc[9]  += al * w2.y; macc[10] += al * w2.z; macc[11] += al * w2.w;
            macc[12] += al * w3.x; macc[13] += al * w3.y; macc[14] += al * w3.z; macc[15] += al * w3.w;
        }
    }
    if (q0 + qq2 < L) {
        int pos = posbase + q0 + qq2;
        float* mp = mpart + (size_t)jhalf * NPOS * OUTF + (size_t)pos * OUTF + h1 * 64 + ddg;
        *(float4*)(mp + 0)  = make_float4(macc[0],  macc[1],  macc[2],  macc[3]);
        *(float4*)(mp + 4)  = make_float4(macc[4],  macc[5],  macc[6],  macc[7]);
        *(float4*)(mp + 8)  = make_float4(macc[8],  macc[9],  macc[10], macc[11]);
        *(float4*)(mp + 12) = make_float4(macc[12], macc[13], macc[14], macc[15]);
    }
}

// ---------------------------------------------------------------------------
// E1: m = mpart0+mpart1; relu; ln1; write concat buffer [H | ln1(relu(m))]
// ---------------------------------------------------------------------------
__global__ __launch_bounds__(256) void e1_relu_ln(
    const float* __restrict__ mpart, const float* __restrict__ Hb,
    const float* __restrict__ g1, const float* __restrict__ b1,
    float* __restrict__ cc)
{
    int w = threadIdx.x >> 6, lane = threadIdx.x & 63;
    int row = blockIdx.x * 4 + w;
    int c = lane * 4;
    float4 x0 = *(const float4*)(mpart + (size_t)row * OUTF + c);
    float4 x1 = *(const float4*)(mpart + (size_t)NPOS * OUTF + (size_t)row * OUTF + c);
    float x[4] = { fmaxf(x0.x + x1.x, 0.f), fmaxf(x0.y + x1.y, 0.f),
                   fmaxf(x0.z + x1.z, 0.f), fmaxf(x0.w + x1.w, 0.f) };
    float s = x[0] + x[1] + x[2] + x[3];
#pragma unroll
    for (int m = 32; m > 0; m >>= 1) s += __shfl_xor(s, m, 64);
    float mu = s * (1.0f / 256.0f);
    float vs = 0.f;
#pragma unroll
    for (int i = 0; i < 4; ++i) { float d = x[i] - mu; vs += d * d; }
#pragma unroll
    for (int m = 32; m > 0; m >>= 1) vs += __shfl_xor(vs, m, 64);
    float rs = rsqrtf(vs * (1.0f / 256.0f) + 1e-5f);
    float4 y;
    y.x = (x[0] - mu) * rs * g1[c + 0] + b1[c + 0];
    y.y = (x[1] - mu) * rs * g1[c + 1] + b1[c + 1];
    y.z = (x[2] - mu) * rs * g1[c + 2] + b1[c + 2];
    y.w = (x[3] - mu) * rs * g1[c + 3] + b1[c + 3];
    *(float4*)(cc + (size_t)row * INF + OUTF + c) = y;
    float4 hh = *(const float4*)(Hb + (size_t)row * OUTF + c);
    *(float4*)(cc + (size_t)row * INF + c) = hh;
}

// ---------------------------------------------------------------------------
// E2: beta = sigmoid(cc @ Wbeta + bbeta); out = beta*m1 + (1-beta)*H
// ---------------------------------------------------------------------------
__global__ __launch_bounds__(256) void e2_beta(
    const float* __restrict__ cc, const float* __restrict__ Wb,
    const float* __restrict__ bb, float* __restrict__ outb)
{
    __shared__ float AT[16][68];
    __shared__ float Bs[16][132];
    int t = threadIdx.x;
    int n0 = blockIdx.x * 128;
    int m0 = blockIdx.y * 64;
    float acc[4][8];
#pragma unroll
    for (int i = 0; i < 4; ++i)
#pragma unroll
        for (int j = 0; j < 8; ++j) acc[i][j] = 0.f;
    int mg = (t >> 4) * 4, jg = (t & 15) * 8;
    int am = t & 63, ak = (t >> 6) * 4;
    int bkk = t >> 4, bn = (t & 15) * 8;
    for (int k0 = 0; k0 < INF; k0 += 16) {
        __syncthreads();
        {
            int row = m0 + am;
            float4 v = make_float4(0.f, 0.f, 0.f, 0.f);
            if (row < NPOS) v = *(const float4*)(cc + (size_t)row * INF + k0 + ak);
            AT[ak + 0][am] = v.x; AT[ak + 1][am] = v.y;
            AT[ak + 2][am] = v.z; AT[ak + 3][am] = v.w;
        }
        {
            const float* p = Wb + (size_t)(k0 + bkk) * OUTF + n0 + bn;
            float4 u0 = *(const float4*)p;
            float4 u1 = *(const float4*)(p + 4);
            *(float4*)&Bs[bkk][bn]     = u0;
            *(float4*)&Bs[bkk][bn + 4] = u1;
        }
        __syncthreads();
#pragma unroll
        for (int kk = 0; kk < 16; ++kk) {
            float4 a  = *(const float4*)&AT[kk][mg];
            float4 b0 = *(const float4*)&Bs[kk][jg];
            float4 b1 = *(const float4*)&Bs[kk][jg + 4];
            float av[4] = {a.x, a.y, a.z, a.w};
            float bv_[8] = {b0.x, b0.y, b0.z, b0.w, b1.x, b1.y, b1.z, b1.w};
#pragma unroll
            for (int i = 0; i < 4; ++i)
#pragma unroll
                for (int j = 0; j < 8; ++j) acc[i][j] += av[i] * bv_[j];
        }
    }
#pragma unroll
    for (int i = 0; i < 4; ++i) {
        int row = m0 + mg + i;
        if (row < NPOS) {
#pragma unroll
            for (int j = 0; j < 8; ++j) {
                int n = n0 + jg + j;
                float x = acc[i][j] + bb[n];
                float sg = 1.0f / (1.0f + __expf(-x));
                float m1v = cc[(size_t)row * INF + OUTF + n];
                float Hv  = cc[(size_t)row * INF + n];
                outb[(size_t)row * OUTF + n] = sg * m1v + (1.0f - sg) * Hv;
            }
        }
    }
}

// ---------------------------------------------------------------------------
// E3: t = out @ w1 + b1 ; ln2(eps=1e-6) ; tanh -> h2.  Block owns 16 full rows.
// ---------------------------------------------------------------------------
__global__ __launch_bounds__(256) void e3_w1_ln2(
    const float* __restrict__ outb, const float* __restrict__ w1,
    const float* __restrict__ b1v, const float* __restrict__ g2,
    const float* __restrict__ b2v, float* __restrict__ h2o)
{
    __shared__ float As[16][260];
    __shared__ float Bs[16][260];
    __shared__ float red[16][17];
    int t = threadIdx.x;
    int m0 = blockIdx.x * 16;
    {
        int rr = t >> 4, c4 = (t & 15) * 4;
        int row = m0 + rr;
#pragma unroll
        for (int i = 0; i < 4; ++i) {
            int c = c4 + i * 64;
            float4 x = make_float4(0.f, 0.f, 0.f, 0.f);
            if (row < NPOS) x = *(const float4*)(outb + (size_t)row * OUTF + c);
            *(float4*)&As[rr][c] = x;
        }
    }
    int q = t & 15, dg = (t >> 4) * 16;
    float acc[16];
#pragma unroll
    for (int i = 0; i < 16; ++i) acc[i] = 0.f;
    for (int k0 = 0; k0 < 256; k0 += 16) {
        __syncthreads();
        {
            int kk = t >> 4, n16 = (t & 15) * 16;
#pragma unroll
            for (int i = 0; i < 4; ++i) {
                float4 x = *(const float4*)(w1 + (size_t)(k0 + kk) * OUTF + n16 + i * 4);
                *(float4*)&Bs[kk][n16 + i * 4] = x;
            }
        }
        __syncthreads();
#pragma unroll
        for (int kk = 0; kk < 16; ++kk) {
            float a = As[q][k0 + kk];
#pragma unroll
            for (int i = 0; i < 16; i += 4) {
                float4 b = *(const float4*)&Bs[kk][dg + i];
                acc[i + 0] += a * b.x; acc[i + 1] += a * b.y;
                acc[i + 2] += a * b.z; acc[i + 3] += a * b.w;
            }
        }
    }
    float x[16];
#pragma unroll
    for (int i = 0; i < 16; ++i) x[i] = acc[i] + b1v[dg + i];
    float ps = 0.f;
#pragma unroll
    for (int i = 0; i < 16; ++i) ps += x[i];
    __syncthreads();
    red[t >> 4][q] = ps;
    __syncthreads();
    float s = 0.f;
#pragma unroll
    for (int i = 0; i < 16; ++i) s += red[i][q];
    float mu = s * (1.0f / 256.0f);
    float pv = 0.f;
#pragma unroll
    for (int i = 0; i < 16; ++i) { float d = x[i] - mu; pv += d * d; }
    __syncthreads();
    red[t >> 4][q] = pv;
    __syncthreads();
    float v = 0.f;
#pragma unroll
    for (int i = 0; i < 16; ++i) v += red[i][q];
    float rs = rsqrtf(v * (1.0f / 256.0f) + 1e-6f);
    int row = m0 + q;
    if (row < NPOS) {
#pragma unroll
        for (int i = 0; i < 16; ++i) {
            int n = dg + i;
            h2o[(size_t)row * OUTF + n] = tanhf((x[i] - mu) * rs * g2[n] + b2v[n]);
        }
    }
}

// ---------------------------------------------------------------------------
// E4: final = h2 @ w2  (no bias) -> d_out
// ---------------------------------------------------------------------------
__global__ __launch_bounds__(256) void e4_final(
    const float* __restrict__ h2in, const float* __restrict__ w2,
    float* __restrict__ outp)
{
    __shared__ float AT[16][68];
    __shared__ float Bs[16][132];
    int t = threadIdx.x;
    int n0 = blockIdx.x * 128;
    int m0 = blockIdx.y * 64;
    float acc[4][8];
#pragma unroll
    for (int i = 0; i < 4; ++i)
#pragma unroll
        for (int j = 0; j < 8; ++j) acc[i][j] = 0.f;
    int mg = (t >> 4) * 4, jg = (t & 15) * 8;
    int am = t & 63, ak = (t >> 6) * 4;
    int bkk = t >> 4, bn = (t & 15) * 8;
    for (int k0 = 0; k0 < 256; k0 += 16) {
        __syncthreads();
        {
            int row = m0 + am;
            float4 v = make_float4(0.f, 0.f, 0.f, 0.f);
            if (row < NPOS) v = *(const float4*)(h2in + (size_t)row * OUTF + k0 + ak);
            AT[ak + 0][am] = v.x; AT[ak + 1][am] = v.y;
            AT[ak + 2][am] = v.z; AT[ak + 3][am] = v.w;
        }
        {
            const float* p = w2 + (size_t)(k0 + bkk) * OUTF + n0 + bn;
            float4 u0 = *(const float4*)p;
            float4 u1 = *(const float4*)(p + 4);
            *(float4*)&Bs[bkk][bn]     = u0;
            *(float4*)&Bs[bkk][bn + 4] = u1;
        }
        __syncthreads();
#pragma unroll
        for (int kk = 0; kk < 16; ++kk) {
            float4 a  = *(const float4*)&AT[kk][mg];
            float4 b0 = *(const float4*)&Bs[kk][jg];
            float4 b1 = *(const float4*)&Bs[kk][jg + 4];
            float av[4] = {a.x, a.y, a.z, a.w};
            float bv_[8] = {b0.x, b0.y, b0.z, b0.w, b1.x, b1.y, b1.z, b1.w};
#pragma unroll
            for (int i = 0; i < 4; ++i)
#pragma unroll
                for (int j = 0; j < 8; ++j) acc[i][j] += av[i] * bv_[j];
        }
    }
#pragma unroll
    for (int i = 0; i < 4; ++i) {
        int row = m0 + mg + i;
        if (row < NPOS) {
#pragma unroll
            for (int j = 0; j < 8; ++j) {
                outp[(size_t)row * OUTF + n0 + jg + j] = acc[i][j];
            }
        }
    }
}

// ---------------------------------------------------------------------------
extern "C" void kernel_launch(void* const* d_in, const int* in_sizes, int n_in,
                              void* d_out, int out_size, void* d_ws, size_t ws_size,
                              hipStream_t stream)
{
    const float* feature = (const float*)d_in[0];
    const float* adj   = (const float*)d_in[1];
    const float* r     = (const float*)d_in[2];
    const float* Wq    = (const float*)d_in[3];
    const float* bq    = (const float*)d_in[4];
    const float* Wk    = (const float*)d_in[5];
    const float* bk    = (const float*)d_in[6];
    const float* Wv    = (const float*)d_in[7];
    const float* bv    = (const float*)d_in[8];
    const float* Ww    = (const float*)d_in[9];
    const float* bw    = (const float*)d_in[10];
    const float* Wr    = (const float*)d_in[11];
    const float* br    = (const float*)d_in[12];
    const float* Wbeta = (const float*)d_in[13];
    const float* bbeta = (const float*)d_in[14];
    const float* ln1g  = (const float*)d_in[15];
    const float* ln1b  = (const float*)d_in[16];
    const float* w1    = (const float*)d_in[17];
    const float* b1    = (const float*)d_in[18];
    const float* ln2g  = (const float*)d_in[19];
    const float* ln2b  = (const float*)d_in[20];
    const float* w2    = (const float*)d_in[21];
    const int*   flag  = (const int*)d_in[22];
    float* out = (float*)d_out;

    char* ws = (char*)d_ws;
    size_t off = 0;
    auto alloc = [&](size_t bytes) -> void* {
        void* p = (void*)(ws + off);
        off += (bytes + 255) & ~(size_t)255;
        return p;
    };
    float* S     = (float*)alloc((size_t)3 * 256 * 4);
    float* hQ    = (float*)alloc((size_t)NPOS * OUTF * 4);
    float* hK    = (float*)alloc((size_t)NPOS * OUTF * 4);
    float* hV    = (float*)alloc((size_t)NPOS * OUTF * 4);
    float* Hb    = (float*)alloc((size_t)NPOS * OUTF * 4);
    float* B1    = (float*)alloc((size_t)512 * JPAD * 4);
    float* B2a   = (float*)alloc((size_t)512 * JPAD * 4);
    float* B2b   = (float*)alloc((size_t)512 * JPAD * 4);
    float* mpart = (float*)alloc((size_t)2 * NPOS * OUTF * 4);
    float* cc    = (float*)alloc((size_t)NPOS * INF * 4);
    float* outb  = (float*)alloc((size_t)NPOS * OUTF * 4);
    float* hh2   = (float*)alloc((size_t)NPOS * OUTF * 4);

    k0_rp<<<1, 256, 0, stream>>>(r, Wr, br, flag, S);
    k1_proj<<<dim3(8, 77), 256, 0, stream>>>(feature, Wq, bq, Wk, bk, Wv, bv, Ww, bw,
                                             hQ, hK, hV, Hb);
    k2_pgemm<<<dim3(39, 8, 3), 256, 0, stream>>>(hK, adj, S, B1, B2a, B2b);
    k3_fused<<<614, 256, 0, stream>>>(hQ, hV, S, B1, B2a, B2b, mpart);
    e1_relu_ln<<<1225, 256, 0, stream>>>(mpart, Hb, ln1g, ln1b, cc);
    e2_beta<<<dim3(2, 77), 256, 0, stream>>>(cc, Wbeta, bbeta, outb);
    e3_w1_ln2<<<307, 256, 0, stream>>>(outb, w1, b1, ln2g, ln2b, hh2);
    e4_final<<<dim3(2, 77), 256, 0, stream>>>(hh2, w2, out);
}

// Round 2
// 2052.002 us; speedup vs baseline: 1.4614x; 1.4614x over previous
//
#include <hip/hip_runtime.h>
#include <hip/hip_bf16.h>
#include <math.h>

#define NPOS 4900
#define NG1  708
#define NG2  4192
#define INF  512
#define OUTF 256
#define JPAD 4904       // padded j-stride for B buffers (mult of 8, >= 4900)
#define JS   384        // logits slab width
#define NSLAB 13        // ceil(4900/384)

// ---------------------------------------------------------------------------
// K0: rp = r @ Wr + br  (4x256); store S[0]=rp[ridx], S[1]=rp[2], S[2]=rp[3]
// ---------------------------------------------------------------------------
__global__ __launch_bounds__(256) void k0_rp(
    const float* __restrict__ r, const float* __restrict__ Wr,
    const float* __restrict__ br, const int* __restrict__ flagp,
    float* __restrict__ S)
{
    __shared__ float rsh[1024];
    int t = threadIdx.x;
    for (int i = t; i < 1024; i += 256) rsh[i] = r[i];
    __syncthreads();
    float a0 = 0.f, a1 = 0.f, a2 = 0.f, a3 = 0.f;
    for (int c = 0; c < 256; ++c) {
        float w = Wr[c * 256 + t];
        a0 += rsh[c] * w;
        a1 += rsh[256 + c] * w;
        a2 += rsh[512 + c] * w;
        a3 += rsh[768 + c] * w;
    }
    float b = br[t];
    a0 += b; a1 += b; a2 += b; a3 += b;
    int ridx = (flagp[0] != 0) ? 1 : 0;
    S[t]         = ridx ? a1 : a0;
    S[256 + t]   = a2;
    S[512 + t]   = a3;
}

// ---------------------------------------------------------------------------
// K1: fused projections hQ/hK/hV/H = feature @ {Wq,Wk,Wv,Ww} + bias
// ---------------------------------------------------------------------------
__global__ __launch_bounds__(256) void k1_proj(
    const float* __restrict__ feat,
    const float* __restrict__ Wq, const float* __restrict__ bq,
    const float* __restrict__ Wk, const float* __restrict__ bk,
    const float* __restrict__ Wv, const float* __restrict__ bv,
    const float* __restrict__ Ww, const float* __restrict__ bw,
    float* __restrict__ hQ, float* __restrict__ hK,
    float* __restrict__ hV, float* __restrict__ Hb)
{
    __shared__ float AT[16][68];    // [k][m]
    __shared__ float Bs[16][132];   // [k][n]
    int t = threadIdx.x;
    int mat = blockIdx.x >> 1;
    int n0  = (blockIdx.x & 1) * 128;
    int m0  = blockIdx.y * 64;
    const float* W; const float* bias; float* dst;
    switch (mat) {
        case 0:  W = Wq; bias = bq; dst = hQ; break;
        case 1:  W = Wk; bias = bk; dst = hK; break;
        case 2:  W = Wv; bias = bv; dst = hV; break;
        default: W = Ww; bias = bw; dst = Hb; break;
    }
    float acc[4][8];
#pragma unroll
    for (int i = 0; i < 4; ++i)
#pragma unroll
        for (int j = 0; j < 8; ++j) acc[i][j] = 0.f;
    int mg = (t >> 4) * 4, jg = (t & 15) * 8;
    int am = t & 63, ak = (t >> 6) * 4;
    int bkk = t >> 4, bn = (t & 15) * 8;
    for (int k0 = 0; k0 < INF; k0 += 16) {
        __syncthreads();
        {
            int row = m0 + am;
            float4 v = make_float4(0.f, 0.f, 0.f, 0.f);
            if (row < NPOS) v = *(const float4*)(feat + (size_t)row * INF + k0 + ak);
            AT[ak + 0][am] = v.x; AT[ak + 1][am] = v.y;
            AT[ak + 2][am] = v.z; AT[ak + 3][am] = v.w;
        }
        {
            const float* p = W + (size_t)(k0 + bkk) * OUTF + n0 + bn;
            float4 u0 = *(const float4*)p;
            float4 u1 = *(const float4*)(p + 4);
            *(float4*)&Bs[bkk][bn]     = u0;
            *(float4*)&Bs[bkk][bn + 4] = u1;
        }
        __syncthreads();
#pragma unroll
        for (int kk = 0; kk < 16; ++kk) {
            float4 a  = *(const float4*)&AT[kk][mg];
            float4 b0 = *(const float4*)&Bs[kk][jg];
            float4 b1 = *(const float4*)&Bs[kk][jg + 4];
            float av[4] = {a.x, a.y, a.z, a.w};
            float bv_[8] = {b0.x, b0.y, b0.z, b0.w, b1.x, b1.y, b1.z, b1.w};
#pragma unroll
            for (int i = 0; i < 4; ++i)
#pragma unroll
                for (int j = 0; j < 8; ++j) acc[i][j] += av[i] * bv_[j];
        }
    }
#pragma unroll
    for (int i = 0; i < 4; ++i) {
        int row = m0 + mg + i;
        if (row < NPOS) {
#pragma unroll
            for (int j = 0; j < 8; ++j) {
                int n = n0 + jg + j;
                dst[(size_t)row * OUTF + n] = acc[i][j] + bias[n];
            }
        }
    }
}

// ---------------------------------------------------------------------------
// K2: B[(v,h,dd)][j] = sum_k (hKview[h*L+k][dd] * 0.5*S[v+part][(k&3)*64+dd]) * adj[krow][j]
// ---------------------------------------------------------------------------
__global__ __launch_bounds__(256) void k2_pgemm(
    const float* __restrict__ hK, const float* __restrict__ adj,
    const float* __restrict__ S,
    float* __restrict__ B1, float* __restrict__ B2a, float* __restrict__ B2b)
{
    __shared__ float AT[16][68];    // [kk][dd]
    __shared__ float Bs[16][132];   // [kk][j]
    int t = threadIdx.x;
    int j0 = blockIdx.x * 128;
    int v = blockIdx.y >> 2, h = blockIdx.y & 3;
    int z = blockIdx.z;
    int part = (z > 0) ? 1 : 0;
    int L = part ? NG2 : NG1;
    int kvbase = part ? (z - 1) * 2096 : 0;
    int Ksteps = part ? 131 : 45;
    const float* kviewbase = hK + (part ? NG1 * OUTF : 0) + (size_t)h * L * 64;
    const float* sv = S + (v + part) * 256;
    int rowoff = part ? NG1 : 0;
    float* dst = (z == 0) ? B1 : ((z == 1) ? B2a : B2b);
    dst += (size_t)((v * 4 + h) * 64) * JPAD;

    float acc[4][8];
#pragma unroll
    for (int i = 0; i < 4; ++i)
#pragma unroll
        for (int j = 0; j < 8; ++j) acc[i][j] = 0.f;
    int ddg = (t >> 4) * 4, jg = (t & 15) * 8;
    int akk = t >> 4, add4 = (t & 15) * 4;
    int bkk = t >> 4, bj = (t & 15) * 8;

    for (int ks = 0; ks < Ksteps; ++ks) {
        int k0 = kvbase + ks * 16;
        __syncthreads();
        {
            int kv = k0 + akk;
            float4 a = make_float4(0.f, 0.f, 0.f, 0.f);
            if (kv < L) {
                float4 x  = *(const float4*)(kviewbase + (size_t)kv * 64 + add4);
                float4 s4 = *(const float4*)(sv + (kv & 3) * 64 + add4);
                a = make_float4(0.5f * x.x * s4.x, 0.5f * x.y * s4.y,
                                0.5f * x.z * s4.z, 0.5f * x.w * s4.w);
            }
            *(float4*)&AT[akk][add4] = a;
        }
        {
            int kv = k0 + bkk;
            int arow = rowoff + kv;
            if (kv < L && (j0 + bj + 7) < NPOS) {
                const float* p = adj + (size_t)arow * NPOS + j0 + bj;
                float4 u0 = *(const float4*)p;
                float4 u1 = *(const float4*)(p + 4);
                *(float4*)&Bs[bkk][bj]     = u0;
                *(float4*)&Bs[bkk][bj + 4] = u1;
            } else {
#pragma unroll
                for (int j = 0; j < 8; ++j) {
                    int jj = j0 + bj + j;
                    Bs[bkk][bj + j] = (kv < L && jj < NPOS)
                        ? adj[(size_t)arow * NPOS + jj] : 0.f;
                }
            }
        }
        __syncthreads();
#pragma unroll
        for (int kk = 0; kk < 16; ++kk) {
            float4 a  = *(const float4*)&AT[kk][ddg];
            float4 b0 = *(const float4*)&Bs[kk][jg];
            float4 b1 = *(const float4*)&Bs[kk][jg + 4];
            float av[4] = {a.x, a.y, a.z, a.w};
            float bv_[8] = {b0.x, b0.y, b0.z, b0.w, b1.x, b1.y, b1.z, b1.w};
#pragma unroll
            for (int i = 0; i < 4; ++i)
#pragma unroll
                for (int j = 0; j < 8; ++j) acc[i][j] += av[i] * bv_[j];
        }
    }
#pragma unroll
    for (int i = 0; i < 4; ++i) {
        float* drow = dst + (size_t)(ddg + i) * JPAD;
#pragma unroll
        for (int j = 0; j < 8; ++j) {
            int jj = j0 + jg + j;
            if (jj < NPOS) drow[jj] = acc[i][j];
        }
    }
}

// ---------------------------------------------------------------------------
// KCOMB: Bc[(g*4+h)*128 + kk][j] = kk<64 ? B1[(g4h)*64+kk][j]
//                                        : B2a[(g4h)*64+kk-64][j] + B2b[...][j]
// cols >= 4900 zeroed.
// ---------------------------------------------------------------------------
__global__ __launch_bounds__(256) void kcomb(
    const float* __restrict__ B1, const float* __restrict__ B2a,
    const float* __restrict__ B2b, float* __restrict__ Bc)
{
    int R = blockIdx.x;          // 0..1023
    int gh = R >> 7, kk = R & 127;
    int t = threadIdx.x;
    float* drow = Bc + (size_t)R * JPAD;
    if (kk < 64) {
        const float* s = B1 + (size_t)(gh * 64 + kk) * JPAD;
        for (int c4 = t * 4; c4 < JPAD; c4 += 1024) {
            float4 v;
            if (c4 + 3 < NPOS) v = *(const float4*)(s + c4);
            else {
                v.x = (c4 + 0 < NPOS) ? s[c4 + 0] : 0.f;
                v.y = (c4 + 1 < NPOS) ? s[c4 + 1] : 0.f;
                v.z = (c4 + 2 < NPOS) ? s[c4 + 2] : 0.f;
                v.w = (c4 + 3 < NPOS) ? s[c4 + 3] : 0.f;
            }
            *(float4*)(drow + c4) = v;
        }
    } else {
        const float* sa = B2a + (size_t)(gh * 64 + kk - 64) * JPAD;
        const float* sb = B2b + (size_t)(gh * 64 + kk - 64) * JPAD;
        for (int c4 = t * 4; c4 < JPAD; c4 += 1024) {
            float4 v;
            if (c4 + 3 < NPOS) {
                float4 a = *(const float4*)(sa + c4);
                float4 b = *(const float4*)(sb + c4);
                v = make_float4(a.x + b.x, a.y + b.y, a.z + b.z, a.w + b.w);
            } else {
                v.x = (c4 + 0 < NPOS) ? sa[c4 + 0] + sb[c4 + 0] : 0.f;
                v.y = (c4 + 1 < NPOS) ? sa[c4 + 1] + sb[c4 + 1] : 0.f;
                v.z = (c4 + 2 < NPOS) ? sa[c4 + 2] + sb[c4 + 2] : 0.f;
                v.w = (c4 + 3 < NPOS) ? sa[c4 + 3] + sb[c4 + 3] : 0.f;
            }
            *(float4*)(drow + c4) = v;
        }
    }
}

// ---------------------------------------------------------------------------
// K3a: logits slab GEMM.  LG[h][pos][jloc] = Q~[h,pos][0:128] . Bc[(g,h)][0:128][j0+jloc]
// Tile M=128 (q), N=128 (j), K=128.  Q~ staged with on-the-fly rp scaling.
// ---------------------------------------------------------------------------
__global__ __launch_bounds__(256) void k3a_logits(
    const float* __restrict__ hQ, const float* __restrict__ S,
    const float* __restrict__ Bc, float* __restrict__ LG, int j0)
{
    __shared__ float As[16][132];    // [kk][m]
    __shared__ float BsA[16][68];    // cols jg..jg+3 (u=jg/8)
    __shared__ float BsB[16][68];    // cols jg+4..jg+7
    int t = threadIdx.x;
    int n0 = blockIdx.x * 128;       // 0,128,256 within slab
    int y = blockIdx.y;              // 156 = 4h * 39
    int h = y / 39, rr = y % 39;
    int g, tile;
    if (rr < 6) { g = 0; tile = rr; } else { g = 1; tile = rr - 6; }
    int Lg = g ? NG2 : NG1;
    int vbase = g ? NG1 * OUTF : 0;
    int posbase = g ? NG1 : 0;
    int q0 = tile * 128;

    float acc[8][8];
#pragma unroll
    for (int i = 0; i < 8; ++i)
#pragma unroll
        for (int j = 0; j < 8; ++j) acc[i][j] = 0.f;
    int mg = (t >> 4) * 8, jg = (t & 15) * 8;
    int u = t & 15;
    int bkk = t >> 4;

    for (int k0 = 0; k0 < 128; k0 += 16) {
        int p = k0 >> 6;
        __syncthreads();
        // stage A (Q scaled): 512 float4 slots, 2 per thread
#pragma unroll
        for (int i = 0; i < 2; ++i) {
            int s = t + i * 256;
            int m = s >> 2, kq = (s & 3) * 4;
            int d = (k0 & 63) + kq;
            int ql = q0 + m;
            float4 v = make_float4(0.f, 0.f, 0.f, 0.f);
            if (ql < Lg) {
                float4 qv = *(const float4*)(hQ + vbase + (size_t)(h * Lg + ql) * 64 + d);
                float4 sv = *(const float4*)(S + (g + p) * 256 + (ql & 3) * 64 + d);
                v = make_float4(qv.x * sv.x, qv.y * sv.y, qv.z * sv.z, qv.w * sv.w);
            }
            As[kq + 0][m] = v.x; As[kq + 1][m] = v.y;
            As[kq + 2][m] = v.z; As[kq + 3][m] = v.w;
        }
        // stage B (de-interleaved into BsA / BsB)
        {
            int row = (g * 4 + h) * 128 + k0 + bkk;
            int col = j0 + n0 + u * 8;
            float4 c0 = make_float4(0.f, 0.f, 0.f, 0.f);
            float4 c1 = make_float4(0.f, 0.f, 0.f, 0.f);
            if (col + 7 < JPAD) {
                const float* pp = Bc + (size_t)row * JPAD + col;
                c0 = *(const float4*)pp;
                c1 = *(const float4*)(pp + 4);
            }
            *(float4*)&BsA[bkk][u * 4] = c0;
            *(float4*)&BsB[bkk][u * 4] = c1;
        }
        __syncthreads();
#pragma unroll
        for (int kk = 0; kk < 16; ++kk) {
            float4 a0 = *(const float4*)&As[kk][mg];
            float4 a1 = *(const float4*)&As[kk][mg + 4];
            float4 b0 = *(const float4*)&BsA[kk][u * 4];
            float4 b1 = *(const float4*)&BsB[kk][u * 4];
            float av[8] = {a0.x, a0.y, a0.z, a0.w, a1.x, a1.y, a1.z, a1.w};
            float bv_[8] = {b0.x, b0.y, b0.z, b0.w, b1.x, b1.y, b1.z, b1.w};
#pragma unroll
            for (int i = 0; i < 8; ++i)
#pragma unroll
                for (int j = 0; j < 8; ++j) acc[i][j] += av[i] * bv_[j];
        }
    }
#pragma unroll
    for (int i = 0; i < 8; ++i) {
        int ql = q0 + mg + i;
        if (ql < Lg) {
            float* pp = LG + ((size_t)h * NPOS + posbase + ql) * JS + n0 + jg;
            *(float4*)pp       = make_float4(acc[i][0], acc[i][1], acc[i][2], acc[i][3]);
            *(float4*)(pp + 4) = make_float4(acc[i][4], acc[i][5], acc[i][6], acc[i][7]);
        }
    }
}

// ---------------------------------------------------------------------------
// K3b: PV slab GEMM with fused head-softmax in A-staging.
// mpart[ks][pos][h*64+d] += sum_{j in ks-range} softmax_h(LG[:, pos, j]) * hV[h][j][d]
// ---------------------------------------------------------------------------
__global__ __launch_bounds__(256) void k3b_pv(
    const float* __restrict__ LG, const float* __restrict__ hV,
    float* __restrict__ mpart, int j0, int first)
{
    __shared__ float As[16][136];    // [jj][pos]
    __shared__ float Bs[16][68];     // [jj][d]
    int t = threadIdx.x;
    int m0 = blockIdx.x * 128;
    int h = blockIdx.y, ks = blockIdx.z;
    int jbase = ks * 192;

    float acc[8][4];
#pragma unroll
    for (int i = 0; i < 8; ++i)
#pragma unroll
        for (int j = 0; j < 4; ++j) acc[i][j] = 0.f;
    int mg = (t >> 4) * 8, dgr = (t & 15) * 4;
    int posl = t >> 1, jh = (t & 1) * 8;

    for (int kc = 0; kc < 192; kc += 16) {
        __syncthreads();
        // stage alpha (softmax over heads from 4 LG planes)
        {
            int pos = m0 + posl;
            float vv[4][8];
            if (pos < NPOS) {
#pragma unroll
                for (int hp = 0; hp < 4; ++hp) {
                    const float* pp = LG + ((size_t)hp * NPOS + pos) * JS + jbase + kc + jh;
                    *(float4*)&vv[hp][0] = *(const float4*)pp;
                    *(float4*)&vv[hp][4] = *(const float4*)(pp + 4);
                }
            } else {
#pragma unroll
                for (int hp = 0; hp < 4; ++hp)
#pragma unroll
                    for (int i = 0; i < 8; ++i) vv[hp][i] = 0.f;
            }
#pragma unroll
            for (int i = 0; i < 8; ++i) {
                float v0 = vv[0][i], v1 = vv[1][i], v2 = vv[2][i], v3 = vv[3][i];
                float mx = fmaxf(fmaxf(v0, v1), fmaxf(v2, v3));
                float e0 = __expf(v0 - mx), e1 = __expf(v1 - mx);
                float e2 = __expf(v2 - mx), e3 = __expf(v3 - mx);
                float sum = e0 + e1 + e2 + e3;
                float eh = (h == 0) ? e0 : (h == 1) ? e1 : (h == 2) ? e2 : e3;
                float a = eh / sum;
                int jglob = j0 + jbase + kc + jh + i;
                if (jglob >= NPOS || pos >= NPOS) a = 0.f;
                As[jh + i][posl] = a;
            }
        }
        // stage V
        {
            int jj = t >> 4, d4 = (t & 15) * 4;
            int jglob = j0 + jbase + kc + jj;
            float4 x = make_float4(0.f, 0.f, 0.f, 0.f);
            if (jglob < NPOS)
                x = *(const float4*)(hV + ((size_t)h * NPOS + jglob) * 64 + d4);
            *(float4*)&Bs[jj][d4] = x;
        }
        __syncthreads();
#pragma unroll
        for (int kk = 0; kk < 16; ++kk) {
            float4 a0 = *(const float4*)&As[kk][mg];
            float4 a1 = *(const float4*)&As[kk][mg + 4];
            float4 b  = *(const float4*)&Bs[kk][dgr];
            float av[8] = {a0.x, a0.y, a0.z, a0.w, a1.x, a1.y, a1.z, a1.w};
#pragma unroll
            for (int i = 0; i < 8; ++i) {
                acc[i][0] += av[i] * b.x;
                acc[i][1] += av[i] * b.y;
                acc[i][2] += av[i] * b.z;
                acc[i][3] += av[i] * b.w;
            }
        }
    }
#pragma unroll
    for (int i = 0; i < 8; ++i) {
        int pos = m0 + mg + i;
        if (pos < NPOS) {
            float* pp = mpart + ((size_t)ks * NPOS + pos) * OUTF + h * 64 + dgr;
            float4 prev = first ? make_float4(0.f, 0.f, 0.f, 0.f) : *(const float4*)pp;
            *(float4*)pp = make_float4(prev.x + acc[i][0], prev.y + acc[i][1],
                                       prev.z + acc[i][2], prev.w + acc[i][3]);
        }
    }
}

// ---------------------------------------------------------------------------
// E1: m = mpart0+mpart1; relu; ln1; write concat buffer [H | ln1(relu(m))]
// ---------------------------------------------------------------------------
__global__ __launch_bounds__(256) void e1_relu_ln(
    const float* __restrict__ mpart, const float* __restrict__ Hb,
    const float* __restrict__ g1, const float* __restrict__ b1,
    float* __restrict__ cc)
{
    int w = threadIdx.x >> 6, lane = threadIdx.x & 63;
    int row = blockIdx.x * 4 + w;
    int c = lane * 4;
    float4 x0 = *(const float4*)(mpart + (size_t)row * OUTF + c);
    float4 x1 = *(const float4*)(mpart + (size_t)NPOS * OUTF + (size_t)row * OUTF + c);
    float x[4] = { fmaxf(x0.x + x1.x, 0.f), fmaxf(x0.y + x1.y, 0.f),
                   fmaxf(x0.z + x1.z, 0.f), fmaxf(x0.w + x1.w, 0.f) };
    float s = x[0] + x[1] + x[2] + x[3];
#pragma unroll
    for (int m = 32; m > 0; m >>= 1) s += __shfl_xor(s, m, 64);
    float mu = s * (1.0f / 256.0f);
    float vs = 0.f;
#pragma unroll
    for (int i = 0; i < 4; ++i) { float d = x[i] - mu; vs += d * d; }
#pragma unroll
    for (int m = 32; m > 0; m >>= 1) vs += __shfl_xor(vs, m, 64);
    float rs = rsqrtf(vs * (1.0f / 256.0f) + 1e-5f);
    float4 y;
    y.x = (x[0] - mu) * rs * g1[c + 0] + b1[c + 0];
    y.y = (x[1] - mu) * rs * g1[c + 1] + b1[c + 1];
    y.z = (x[2] - mu) * rs * g1[c + 2] + b1[c + 2];
    y.w = (x[3] - mu) * rs * g1[c + 3] + b1[c + 3];
    *(float4*)(cc + (size_t)row * INF + OUTF + c) = y;
    float4 hh = *(const float4*)(Hb + (size_t)row * OUTF + c);
    *(float4*)(cc + (size_t)row * INF + c) = hh;
}

// ---------------------------------------------------------------------------
// E2: beta = sigmoid(cc @ Wbeta + bbeta); out = beta*m1 + (1-beta)*H
// ---------------------------------------------------------------------------
__global__ __launch_bounds__(256) void e2_beta(
    const float* __restrict__ cc, const float* __restrict__ Wb,
    const float* __restrict__ bb, float* __restrict__ outb)
{
    __shared__ float AT[16][68];
    __shared__ float Bs[16][132];
    int t = threadIdx.x;
    int n0 = blockIdx.x * 128;
    int m0 = blockIdx.y * 64;
    float acc[4][8];
#pragma unroll
    for (int i = 0; i < 4; ++i)
#pragma unroll
        for (int j = 0; j < 8; ++j) acc[i][j] = 0.f;
    int mg = (t >> 4) * 4, jg = (t & 15) * 8;
    int am = t & 63, ak = (t >> 6) * 4;
    int bkk = t >> 4, bn = (t & 15) * 8;
    for (int k0 = 0; k0 < INF; k0 += 16) {
        __syncthreads();
        {
            int row = m0 + am;
            float4 v = make_float4(0.f, 0.f, 0.f, 0.f);
            if (row < NPOS) v = *(const float4*)(cc + (size_t)row * INF + k0 + ak);
            AT[ak + 0][am] = v.x; AT[ak + 1][am] = v.y;
            AT[ak + 2][am] = v.z; AT[ak + 3][am] = v.w;
        }
        {
            const float* p = Wb + (size_t)(k0 + bkk) * OUTF + n0 + bn;
            float4 u0 = *(const float4*)p;
            float4 u1 = *(const float4*)(p + 4);
            *(float4*)&Bs[bkk][bn]     = u0;
            *(float4*)&Bs[bkk][bn + 4] = u1;
        }
        __syncthreads();
#pragma unroll
        for (int kk = 0; kk < 16; ++kk) {
            float4 a  = *(const float4*)&AT[kk][mg];
            float4 b0 = *(const float4*)&Bs[kk][jg];
            float4 b1 = *(const float4*)&Bs[kk][jg + 4];
            float av[4] = {a.x, a.y, a.z, a.w};
            float bv_[8] = {b0.x, b0.y, b0.z, b0.w, b1.x, b1.y, b1.z, b1.w};
#pragma unroll
            for (int i = 0; i < 4; ++i)
#pragma unroll
                for (int j = 0; j < 8; ++j) acc[i][j] += av[i] * bv_[j];
        }
    }
#pragma unroll
    for (int i = 0; i < 4; ++i) {
        int row = m0 + mg + i;
        if (row < NPOS) {
#pragma unroll
            for (int j = 0; j < 8; ++j) {
                int n = n0 + jg + j;
                float x = acc[i][j] + bb[n];
                float sg = 1.0f / (1.0f + __expf(-x));
                float m1v = cc[(size_t)row * INF + OUTF + n];
                float Hv  = cc[(size_t)row * INF + n];
                outb[(size_t)row * OUTF + n] = sg * m1v + (1.0f - sg) * Hv;
            }
        }
    }
}

// ---------------------------------------------------------------------------
// E3: t = out @ w1 + b1 ; ln2(eps=1e-6) ; tanh -> h2.
// ---------------------------------------------------------------------------
__global__ __launch_bounds__(256) void e3_w1_ln2(
    const float* __restrict__ outb, const float* __restrict__ w1,
    const float* __restrict__ b1v, const float* __restrict__ g2,
    const float* __restrict__ b2v, float* __restrict__ h2o)
{
    __shared__ float As[16][260];
    __shared__ float Bs[16][260];
    __shared__ float red[16][17];
    int t = threadIdx.x;
    int m0 = blockIdx.x * 16;
    {
        int rr = t >> 4, c4 = (t & 15) * 4;
        int row = m0 + rr;
#pragma unroll
        for (int i = 0; i < 4; ++i) {
            int c = c4 + i * 64;
            float4 x = make_float4(0.f, 0.f, 0.f, 0.f);
            if (row < NPOS) x = *(const float4*)(outb + (size_t)row * OUTF + c);
            *(float4*)&As[rr][c] = x;
        }
    }
    int q = t & 15, dg = (t >> 4) * 16;
    float acc[16];
#pragma unroll
    for (int i = 0; i < 16; ++i) acc[i] = 0.f;
    for (int k0 = 0; k0 < 256; k0 += 16) {
        __syncthreads();
        {
            int kk = t >> 4, n16 = (t & 15) * 16;
#pragma unroll
            for (int i = 0; i < 4; ++i) {
                float4 x = *(const float4*)(w1 + (size_t)(k0 + kk) * OUTF + n16 + i * 4);
                *(float4*)&Bs[kk][n16 + i * 4] = x;
            }
        }
        __syncthreads();
#pragma unroll
        for (int kk = 0; kk < 16; ++kk) {
            float a = As[q][k0 + kk];
#pragma unroll
            for (int i = 0; i < 16; i += 4) {
                float4 b = *(const float4*)&Bs[kk][dg + i];
                acc[i + 0] += a * b.x; acc[i + 1] += a * b.y;
                acc[i + 2] += a * b.z; acc[i + 3] += a * b.w;
            }
        }
    }
    float x[16];
#pragma unroll
    for (int i = 0; i < 16; ++i) x[i] = acc[i] + b1v[dg + i];
    float ps = 0.f;
#pragma unroll
    for (int i = 0; i < 16; ++i) ps += x[i];
    __syncthreads();
    red[t >> 4][q] = ps;
    __syncthreads();
    float s = 0.f;
#pragma unroll
    for (int i = 0; i < 16; ++i) s += red[i][q];
    float mu = s * (1.0f / 256.0f);
    float pv = 0.f;
#pragma unroll
    for (int i = 0; i < 16; ++i) { float d = x[i] - mu; pv += d * d; }
    __syncthreads();
    red[t >> 4][q] = pv;
    __syncthreads();
    float v = 0.f;
#pragma unroll
    for (int i = 0; i < 16; ++i) v += red[i][q];
    float rs = rsqrtf(v * (1.0f / 256.0f) + 1e-6f);
    int row = m0 + q;
    if (row < NPOS) {
#pragma unroll
        for (int i = 0; i < 16; ++i) {
            int n = dg + i;
            h2o[(size_t)row * OUTF + n] = tanhf((x[i] - mu) * rs * g2[n] + b2v[n]);
        }
    }
}

// ---------------------------------------------------------------------------
// E4: final = h2 @ w2  (no bias) -> d_out
// ---------------------------------------------------------------------------
__global__ __launch_bounds__(256) void e4_final(
    const float* __restrict__ h2in, const float* __restrict__ w2,
    float* __restrict__ outp)
{
    __shared__ float AT[16][68];
    __shared__ float Bs[16][132];
    int t = threadIdx.x;
    int n0 = blockIdx.x * 128;
    int m0 = blockIdx.y * 64;
    float acc[4][8];
#pragma unroll
    for (int i = 0; i < 4; ++i)
#pragma unroll
        for (int j = 0; j < 8; ++j) acc[i][j] = 0.f;
    int mg = (t >> 4) * 4, jg = (t & 15) * 8;
    int am = t & 63, ak = (t >> 6) * 4;
    int bkk = t >> 4, bn = (t & 15) * 8;
    for (int k0 = 0; k0 < 256; k0 += 16) {
        __syncthreads();
        {
            int row = m0 + am;
            float4 v = make_float4(0.f, 0.f, 0.f, 0.f);
            if (row < NPOS) v = *(const float4*)(h2in + (size_t)row * OUTF + k0 + ak);
            AT[ak + 0][am] = v.x; AT[ak + 1][am] = v.y;
            AT[ak + 2][am] = v.z; AT[ak + 3][am] = v.w;
        }
        {
            const float* p = w2 + (size_t)(k0 + bkk) * OUTF + n0 + bn;
            float4 u0 = *(const float4*)p;
            float4 u1 = *(const float4*)(p + 4);
            *(float4*)&Bs[bkk][bn]     = u0;
            *(float4*)&Bs[bkk][bn + 4] = u1;
        }
        __syncthreads();
#pragma unroll
        for (int kk = 0; kk < 16; ++kk) {
            float4 a  = *(const float4*)&AT[kk][mg];
            float4 b0 = *(const float4*)&Bs[kk][jg];
            float4 b1 = *(const float4*)&Bs[kk][jg + 4];
            float av[4] = {a.x, a.y, a.z, a.w};
            float bv_[8] = {b0.x, b0.y, b0.z, b0.w, b1.x, b1.y, b1.z, b1.w};
#pragma unroll
            for (int i = 0; i < 4; ++i)
#pragma unroll
                for (int j = 0; j < 8; ++j) acc[i][j] += av[i] * bv_[j];
        }
    }
#pragma unroll
    for (int i = 0; i < 4; ++i) {
        int row = m0 + mg + i;
        if (row < NPOS) {
#pragma unroll
            for (int j = 0; j < 8; ++j) {
                outp[(size_t)row * OUTF + n0 + jg + j] = acc[i][j];
            }
        }
    }
}

// ---------------------------------------------------------------------------
extern "C" void kernel_launch(void* const* d_in, const int* in_sizes, int n_in,
                              void* d_out, int out_size, void* d_ws, size_t ws_size,
                              hipStream_t stream)
{
    const float* feature = (const float*)d_in[0];
    const float* adj   = (const float*)d_in[1];
    const float* r     = (const float*)d_in[2];
    const float* Wq    = (const float*)d_in[3];
    const float* bq    = (const float*)d_in[4];
    const float* Wk    = (const float*)d_in[5];
    const float* bk    = (const float*)d_in[6];
    const float* Wv    = (const float*)d_in[7];
    const float* bv    = (const float*)d_in[8];
    const float* Ww    = (const float*)d_in[9];
    const float* bw    = (const float*)d_in[10];
    const float* Wr    = (const float*)d_in[11];
    const float* br    = (const float*)d_in[12];
    const float* Wbeta = (const float*)d_in[13];
    const float* bbeta = (const float*)d_in[14];
    const float* ln1g  = (const float*)d_in[15];
    const float* ln1b  = (const float*)d_in[16];
    const float* w1    = (const float*)d_in[17];
    const float* b1    = (const float*)d_in[18];
    const float* ln2g  = (const float*)d_in[19];
    const float* ln2b  = (const float*)d_in[20];
    const float* w2    = (const float*)d_in[21];
    const int*   flag  = (const int*)d_in[22];
    float* out = (float*)d_out;

    // --- workspace layout (explicit offsets, with liveness-based aliasing) ---
    // [0, 30130176)      : B1 | B2a | B2b  (each 512*4904*4 = 10,043,392)
    //                      aliased later by LG (4*4900*384*4 = 30,105,600)
    // [30130176, 40165376): hQ | hK  ; aliased later by cc (4900*512*4)
    // [40165376, 45182976): hV       ; aliased later by outb
    // [45182976, 50200576): Hb       ; aliased later by hh2
    // [50200576, 70287360): Bc  (1024*4904*4 = 20,086,784)
    // [70287360, 80322560): mpart (2*4900*256*4)
    // [80322560, 80325632): S (3*256*4)
    char* ws = (char*)d_ws;
    float* B1    = (float*)(ws + 0);
    float* B2a   = (float*)(ws + 10043392);
    float* B2b   = (float*)(ws + 20086784);
    float* LG    = (float*)(ws + 0);
    float* hQ    = (float*)(ws + 30130176);
    float* hK    = (float*)(ws + 35147776);
    float* cc    = (float*)(ws + 30130176);
    float* hV    = (float*)(ws + 40165376);
    float* outb  = (float*)(ws + 40165376);
    float* Hb    = (float*)(ws + 45182976);
    float* hh2   = (float*)(ws + 45182976);
    float* Bc    = (float*)(ws + 50200576);
    float* mpart = (float*)(ws + 70287360);
    float* S     = (float*)(ws + 80322560);

    k0_rp<<<1, 256, 0, stream>>>(r, Wr, br, flag, S);
    k1_proj<<<dim3(8, 77), 256, 0, stream>>>(feature, Wq, bq, Wk, bk, Wv, bv, Ww, bw,
                                             hQ, hK, hV, Hb);
    k2_pgemm<<<dim3(39, 8, 3), 256, 0, stream>>>(hK, adj, S, B1, B2a, B2b);
    kcomb<<<1024, 256, 0, stream>>>(B1, B2a, B2b, Bc);
    for (int s = 0; s < NSLAB; ++s) {
        int j0 = s * JS;
        k3a_logits<<<dim3(3, 156), 256, 0, stream>>>(hQ, S, Bc, LG, j0);
        k3b_pv<<<dim3(39, 4, 2), 256, 0, stream>>>(LG, hV, mpart, j0, s == 0 ? 1 : 0);
    }
    e1_relu_ln<<<1225, 256, 0, stream>>>(mpart, Hb, ln1g, ln1b, cc);
    e2_beta<<<dim3(2, 77), 256, 0, stream>>>(cc, Wbeta, bbeta, outb);
    e3_w1_ln2<<<307, 256, 0, stream>>>(outb, w1, b1, ln2g, ln2b, hh2);
    e4_final<<<dim3(2, 77), 256, 0, stream>>>(hh2, w2, out);
}